// Round 12
// baseline (270.883 us; speedup 1.0000x reference)
//
#include <hip/hip_runtime.h>
#include <hip/hip_bf16.h>

#define BATCH 2
#define SEQ 2048
#define HID 1024
#define NHEAD 16
#define HDIM 64
// softmax in exp2 domain: logit2 = (q.k) * TEMP_K/sqrt(d) * log2(e)
#define L2SCALE 180.3368800721f
#define NEGBIG (-1.0e30f)

typedef __bf16 bf16;
typedef __bf16 bf16x4 __attribute__((ext_vector_type(4)));
typedef __bf16 bf16x8 __attribute__((ext_vector_type(8)));
typedef float f32x16 __attribute__((ext_vector_type(16)));

union BQ  { bf16x4 v; unsigned u[2]; };
union BF8 { bf16x8 v; unsigned u[4]; };

// Split-K attention item table (heavy-first).
__device__ __constant__ int TAB_QT[30]  = {5,6,7,8,9,10,11,11,12,12,13,13,14,14,15,15, 4,10, 3,9,15, 2,8,14, 1,7,13, 0,6,12};
__device__ __constant__ int TAB_K0[30]  = {0,0,0,0,0,0,0,12,0,12,0,12,0,12,0,12, 0,12, 0,12,24, 0,12,24, 0,12,24, 0,12,24};
__device__ __constant__ int TAB_NIT[30] = {12,12,12,12,12,12,12,12,12,12,12,12,12,12,12,12, 10,10, 8,8,8, 6,6,6, 4,4,4, 2,2,2};
__device__ __constant__ int TAB_PID[30] = {-1,0,2,4,6,8,10,11,12,13,15,16,18,19,21,22, -1,9, -1,7,23, -1,5,20, -1,3,17, -1,1,14};

// ---------------------------------------------------------------------------
// Fused prep: xsplit (blocks 0..4095), W_qkv transpose+split (next 768),
// W_out transpose (last 256).
// ---------------------------------------------------------------------------
__device__ __forceinline__ void transpose_split_body(
    float (*T)[65], const float* __restrict__ W, bf16* __restrict__ Thi,
    bf16* __restrict__ Tlo, int K, int N, int kBase, int nBase, int tid)
{
    {
        const int k0 = tid >> 4;
        const int nc = (tid & 15) * 4;
#pragma unroll
        for (int kk = 0; kk < 4; kk++) {
            int k = k0 + kk * 16;
            float4 v = *(const float4*)(W + (size_t)(kBase + k) * N + nBase + nc);
            T[k][nc] = v.x; T[k][nc + 1] = v.y; T[k][nc + 2] = v.z; T[k][nc + 3] = v.w;
        }
    }
    __syncthreads();
    {
        const int n = tid >> 2;
        const int kc = (tid & 3) * 16;
        bf16x8 h0, h1, l0, l1;
#pragma unroll
        for (int j = 0; j < 8; j++) {
            float a = T[kc + j][n];
            float c = T[kc + 8 + j][n];
            bf16 ha = (bf16)a, hc = (bf16)c;
            h0[j] = ha; h1[j] = hc;
            l0[j] = (bf16)(a - (float)ha);
            l1[j] = (bf16)(c - (float)hc);
        }
        size_t dst = (size_t)(nBase + n) * K + kBase + kc;
        *(bf16x8*)(Thi + dst)     = h0;
        *(bf16x8*)(Thi + dst + 8) = h1;
        if (Tlo) {
            *(bf16x8*)(Tlo + dst)     = l0;
            *(bf16x8*)(Tlo + dst + 8) = l1;
        }
    }
}

__global__ __launch_bounds__(256) void prep_kernel(
    const float* __restrict__ X, bf16* __restrict__ Xhi, bf16* __restrict__ Xlo,
    const float* __restrict__ Wqkv, bf16* __restrict__ Wthi, bf16* __restrict__ Wtlo,
    const float* __restrict__ Wout, bf16* __restrict__ Wot)
{
    __shared__ float T[64][65];
    const int tid = threadIdx.x;
    const int bid = blockIdx.x;
    if (bid < 4096) {
        const int i = bid * 256 + tid;   // one float4 of X per thread
        float4 v = ((const float4*)X)[i];
        float xs[4] = {v.x, v.y, v.z, v.w};
        bf16x4 h, l;
#pragma unroll
        for (int j = 0; j < 4; j++) {
            h[j] = (bf16)xs[j];
            l[j] = (bf16)(xs[j] - (float)h[j]);
        }
        ((bf16x4*)Xhi)[i] = h;
        ((bf16x4*)Xlo)[i] = l;
    } else if (bid < 4096 + 768) {
        const int r = bid - 4096;                       // 16 kTiles x 48 nTiles
        transpose_split_body(T, Wqkv, Wthi, Wtlo, HID, 3 * HID,
                             (r / 48) * 64, (r % 48) * 64, tid);
    } else {
        const int r = bid - 4864;                       // 16 x 16
        transpose_split_body(T, Wout, Wot, nullptr, HID, HID,
                             (r / 16) * 64, (r % 16) * 64, tid);
    }
}

// ---------------------------------------------------------------------------
// Prep C: per-head V transpose [b][h][s][d] -> [b][h][d][s].
// ---------------------------------------------------------------------------
__global__ __launch_bounds__(256) void vtrans_kernel(
    const bf16* __restrict__ vv, bf16* __restrict__ vtr)
{
    __shared__ bf16 T[64][72];
    const int tid = threadIdx.x;
    const int bh = blockIdx.y;
    const int st = blockIdx.x;
    const int r  = tid >> 2;
    const int c0 = (tid & 3) * 16;
    const bf16* src = vv + ((size_t)bh * SEQ + st * 64) * HDIM;
    bf16x8 a = *(const bf16x8*)(src + (size_t)r * HDIM + c0);
    bf16x8 b = *(const bf16x8*)(src + (size_t)r * HDIM + c0 + 8);
    *(bf16x8*)&T[r][c0]     = a;
    *(bf16x8*)&T[r][c0 + 8] = b;
    __syncthreads();
    bf16x8 o0, o1;
#pragma unroll
    for (int i = 0; i < 8; i++) {
        o0[i] = T[c0 + i][r];
        o1[i] = T[c0 + 8 + i][r];
    }
    bf16* dst = vtr + ((size_t)bh * HDIM + r) * SEQ + st * 64 + c0;
    *(bf16x8*)(dst)     = o0;
    *(bf16x8*)(dst + 8) = o1;
}

// ---------------------------------------------------------------------------
// GEMM1 (MFMA): qkv = x @ W_qkv + b_qkv, pre-split bf16.
// r12: r10 tile (128s x 128n, VGPR 80 — the measured structural optimum)
// with LDS staging layout changed to the attention-verified conflict-free
// form: QUAD staging (qr=tid>>2, qc=(tid&3)*8; each thread stages rows qr
// and 64+qr) + PITCH 56 (28 dwords: read starts 28*lm mod 32 tile all 8
// bank groups; write pattern <=2 lanes/bank = free). r10's pitch-40 pair
// staging (sr=tid>>1) collided on writes -> 5.24M conflict cycles.
// Instruction counts identical to r10; numerics untouched.
// ---------------------------------------------------------------------------
__global__ __launch_bounds__(256) void gemm_qkv_mfma(
    const bf16* __restrict__ Xhi, const bf16* __restrict__ Xlo,
    const bf16* __restrict__ Wthi, const bf16* __restrict__ Wtlo,
    const float* __restrict__ bias,
    bf16* __restrict__ qhi, bf16* __restrict__ qlo,
    bf16* __restrict__ khi, bf16* __restrict__ klo, bf16* __restrict__ vv)
{
    __shared__ __align__(16) bf16 Xh[128][56];
    __shared__ __align__(16) bf16 Xl[128][56];
    __shared__ __align__(16) bf16 Wh[128][56];
    __shared__ __align__(16) bf16 Wl[128][56];

    const int tid = threadIdx.x;
    const int wave = tid >> 6, lane = tid & 63;
    const int lm = lane & 31, lq2 = lane >> 5;
    const int wave_s = wave & 1, wave_n = wave >> 1;
    const int nBase = blockIdx.x * 128;
    const int sBase = blockIdx.y * 128;
    const bool isV = (nBase >= 2 * HID);

    // quad staging: thread stages rows qr and 64+qr, 16B chunk qc
    const int qr = tid >> 2;          // 0..63
    const int qc = (tid & 3) * 8;     // 0,8,16,24 (bf16 units)

    f32x16 acc[2][2];
#pragma unroll
    for (int st = 0; st < 2; st++)
#pragma unroll
      for (int nt = 0; nt < 2; nt++)
#pragma unroll
        for (int r = 0; r < 16; r++) acc[st][nt][r] = 0.f;

    // global staging source pointers (rows qr and 64+qr of each tile)
    const bf16* xp0h = Xhi + (size_t)(sBase + qr) * HID + qc;
    const bf16* xp1h = Xhi + (size_t)(sBase + 64 + qr) * HID + qc;
    const bf16* xp0l = Xlo + (size_t)(sBase + qr) * HID + qc;
    const bf16* xp1l = Xlo + (size_t)(sBase + 64 + qr) * HID + qc;
    const bf16* wp0h = Wthi + (size_t)(nBase + qr) * HID + qc;
    const bf16* wp1h = Wthi + (size_t)(nBase + 64 + qr) * HID + qc;
    const bf16* wp0l = Wtlo + (size_t)(nBase + qr) * HID + qc;
    const bf16* wp1l = Wtlo + (size_t)(nBase + 64 + qr) * HID + qc;

    // prologue: staging regs for k0=0
    bf16x8 cx[2], cw[2], cxl[2] = {}, cwl[2] = {};
    cx[0] = *(const bf16x8*)(xp0h);
    cx[1] = *(const bf16x8*)(xp1h);
    cw[0] = *(const bf16x8*)(wp0h);
    cw[1] = *(const bf16x8*)(wp1h);
    if (!isV) {
        cxl[0] = *(const bf16x8*)(xp0l);
        cxl[1] = *(const bf16x8*)(xp1l);
        cwl[0] = *(const bf16x8*)(wp0l);
        cwl[1] = *(const bf16x8*)(wp1l);
    }

    for (int k0 = 0; k0 < HID; k0 += 32) {
        __syncthreads();
        *(bf16x8*)&Xh[qr][qc]      = cx[0];
        *(bf16x8*)&Xh[64 + qr][qc] = cx[1];
        *(bf16x8*)&Wh[qr][qc]      = cw[0];
        *(bf16x8*)&Wh[64 + qr][qc] = cw[1];
        if (!isV) {
            *(bf16x8*)&Xl[qr][qc]      = cxl[0];
            *(bf16x8*)&Xl[64 + qr][qc] = cxl[1];
            *(bf16x8*)&Wl[qr][qc]      = cwl[0];
            *(bf16x8*)&Wl[64 + qr][qc] = cwl[1];
        }
        __syncthreads();

        // prefetch next k-tile into regs (hidden under MFMA below)
        bf16x8 nx[2] = {}, nw[2] = {}, nxl[2] = {}, nwl[2] = {};
        if (k0 + 32 < HID) {
            nx[0] = *(const bf16x8*)(xp0h + k0 + 32);
            nx[1] = *(const bf16x8*)(xp1h + k0 + 32);
            nw[0] = *(const bf16x8*)(wp0h + k0 + 32);
            nw[1] = *(const bf16x8*)(wp1h + k0 + 32);
            if (!isV) {
                nxl[0] = *(const bf16x8*)(xp0l + k0 + 32);
                nxl[1] = *(const bf16x8*)(xp1l + k0 + 32);
                nwl[0] = *(const bf16x8*)(wp0l + k0 + 32);
                nwl[1] = *(const bf16x8*)(wp1l + k0 + 32);
            }
        }

#pragma unroll
        for (int kh = 0; kh < 2; kh++) {
            const int ko = kh * 16 + lq2 * 8;
            bf16x8 aWh[2], aWl[2], bXh[2], bXl[2];
#pragma unroll
            for (int nt = 0; nt < 2; nt++) {
                aWh[nt] = *(bf16x8*)&Wh[wave_n * 64 + nt * 32 + lm][ko];
                if (!isV) aWl[nt] = *(bf16x8*)&Wl[wave_n * 64 + nt * 32 + lm][ko];
            }
#pragma unroll
            for (int st = 0; st < 2; st++) {
                bXh[st] = *(bf16x8*)&Xh[wave_s * 64 + st * 32 + lm][ko];
                if (!isV) bXl[st] = *(bf16x8*)&Xl[wave_s * 64 + st * 32 + lm][ko];
            }
#pragma unroll
            for (int nt = 0; nt < 2; nt++)
#pragma unroll
              for (int st = 0; st < 2; st++) {
                acc[st][nt] = __builtin_amdgcn_mfma_f32_32x32x16_bf16(aWh[nt], bXh[st], acc[st][nt], 0, 0, 0);
                if (!isV) {
                    acc[st][nt] = __builtin_amdgcn_mfma_f32_32x32x16_bf16(aWh[nt], bXl[st], acc[st][nt], 0, 0, 0);
                    acc[st][nt] = __builtin_amdgcn_mfma_f32_32x32x16_bf16(aWl[nt], bXh[st], acc[st][nt], 0, 0, 0);
                }
              }
        }
        cx[0] = nx[0]; cx[1] = nx[1]; cw[0] = nw[0]; cw[1] = nw[1];
        cxl[0] = nxl[0]; cxl[1] = nxl[1]; cwl[0] = nwl[0]; cwl[1] = nwl[1];
    }

    // epilogue: lane owns seq-row s (per st); cols n quad-contiguous
#pragma unroll
    for (int st = 0; st < 2; st++) {
        int s = sBase + wave_s * 64 + st * 32 + lm;
        int bb = s >> 11, ss = s & 2047;
#pragma unroll
        for (int nt = 0; nt < 2; nt++) {
#pragma unroll
            for (int q4 = 0; q4 < 4; q4++) {
                int n = nBase + wave_n * 64 + nt * 32 + 8 * q4 + 4 * lq2;
                float4 bv = *(const float4*)(bias + n);
                float vals[4];
                vals[0] = acc[st][nt][q4 * 4 + 0] + bv.x;
                vals[1] = acc[st][nt][q4 * 4 + 1] + bv.y;
                vals[2] = acc[st][nt][q4 * 4 + 2] + bv.z;
                vals[3] = acc[st][nt][q4 * 4 + 3] + bv.w;
                int which = n >> 10, h = (n >> 6) & 15, d = n & 63;
                size_t dst = (((size_t)bb * NHEAD + h) * SEQ + ss) * HDIM + d;
                if (which < 2) {
                    bf16x4 hi4, lo4;
#pragma unroll
                    for (int i = 0; i < 4; i++) {
                        hi4[i] = (bf16)vals[i];
                        lo4[i] = (bf16)(vals[i] - (float)hi4[i]);
                    }
                    bf16* ph = (which == 0) ? qhi : khi;
                    bf16* pl = (which == 0) ? qlo : klo;
                    *(bf16x4*)(ph + dst) = hi4;
                    *(bf16x4*)(pl + dst) = lo4;
                } else {
                    bf16x4 v4;
#pragma unroll
                    for (int i = 0; i < 4; i++) v4[i] = (bf16)vals[i];
                    *(bf16x4*)(vv + dst) = v4;
                }
            }
        }
    }
}

// ---------------------------------------------------------------------------
// MFMA flash attention, SPLIT-K (unchanged from round 6).
// ---------------------------------------------------------------------------
__global__ __launch_bounds__(256) void attn_kernel(
    const bf16* __restrict__ Qhi, const bf16* __restrict__ Qlo,
    const bf16* __restrict__ Khg, const bf16* __restrict__ Klg,
    const bf16* __restrict__ Vtr, bf16* __restrict__ attnbuf,
    bf16* __restrict__ PartO, float* __restrict__ Mls)
{
    __shared__ __align__(16) bf16 Khs[64][72];
    __shared__ __align__(16) bf16 Kls[64][72];
    __shared__ __align__(16) bf16 Vt [64][72];

    const int tid  = threadIdx.x;
    const int wave = tid >> 6;
    const int lane = tid & 63;
    const int lm   = lane & 31;
    const int lq2  = lane >> 5;

    const int kr  = tid >> 2;
    const int kd0 = (tid & 3) * 16;

    const int slot = blockIdx.x >> 5;
    const int bh   = blockIdx.x & 31;
    const int qt   = TAB_QT[slot];
    const int kt0  = TAB_K0[slot];
    const int nit  = TAB_NIT[slot];
    const int pid  = TAB_PID[slot];
    const int b = bh >> 4, h = bh & 15;
    const size_t headoff = ((size_t)b * NHEAD + h) * SEQ * HDIM;

    const int ql_loc = wave * 32 + lm;
    const int qg = qt * 128 + ql_loc;
    bf16x8 qh[4], qlr[4];
    {
        const bf16* qph = Qhi + headoff + (size_t)qg * HDIM;
        const bf16* qpl = Qlo + headoff + (size_t)qg * HDIM;
#pragma unroll
        for (int c = 0; c < 4; c++) {
            qh[c]  = *(const bf16x8*)(qph + c * 16 + lq2 * 8);
            qlr[c] = *(const bf16x8*)(qpl + c * 16 + lq2 * 8);
        }
    }

    f32x16 O0, O1;
#pragma unroll
    for (int r = 0; r < 16; r++) { O0[r] = 0.f; O1[r] = 0.f; }
    float m_run = NEGBIG, l_run = 0.f;

    const int wave_qmin = qt * 128 + wave * 32;
    const int ktend = kt0 + nit;

    bf16x8 kc[4], vc[2];
    {
        size_t kg = headoff + (size_t)(kt0 * 64 + kr) * HDIM + kd0;
        kc[0] = *(const bf16x8*)(Khg + kg);
        kc[1] = *(const bf16x8*)(Khg + kg + 8);
        kc[2] = *(const bf16x8*)(Klg + kg);
        kc[3] = *(const bf16x8*)(Klg + kg + 8);
        size_t vg = headoff + (size_t)kr * SEQ + kt0 * 64 + kd0;
        vc[0] = *(const bf16x8*)(Vtr + vg);
        vc[1] = *(const bf16x8*)(Vtr + vg + 8);
    }

    for (int kt = kt0; kt < ktend; kt++) {
        __syncthreads();
        *(bf16x8*)&Khs[kr][kd0]     = kc[0];
        *(bf16x8*)&Khs[kr][kd0 + 8] = kc[1];
        *(bf16x8*)&Kls[kr][kd0]     = kc[2];
        *(bf16x8*)&Kls[kr][kd0 + 8] = kc[3];
        *(bf16x8*)&Vt[kr][kd0]      = vc[0];
        *(bf16x8*)&Vt[kr][kd0 + 8]  = vc[1];
        __syncthreads();

        bf16x8 kn[4], vn[2];
        const bool more = (kt + 1 < ktend);
        if (more) {
            size_t kg = headoff + (size_t)((kt + 1) * 64 + kr) * HDIM + kd0;
            kn[0] = *(const bf16x8*)(Khg + kg);
            kn[1] = *(const bf16x8*)(Khg + kg + 8);
            kn[2] = *(const bf16x8*)(Klg + kg);
            kn[3] = *(const bf16x8*)(Klg + kg + 8);
            size_t vg = headoff + (size_t)kr * SEQ + (kt + 1) * 64 + kd0;
            vn[0] = *(const bf16x8*)(Vtr + vg);
            vn[1] = *(const bf16x8*)(Vtr + vg + 8);
        }

        if (kt * 64 <= wave_qmin + 31) {
            f32x16 s[2];
#pragma unroll
            for (int r = 0; r < 16; r++) { s[0][r] = 0.f; s[1][r] = 0.f; }
#pragma unroll
            for (int c = 0; c < 4; c++) {
                bf16x8 ah0 = *(bf16x8*)&Khs[lm][c * 16 + lq2 * 8];
                bf16x8 al0 = *(bf16x8*)&Kls[lm][c * 16 + lq2 * 8];
                bf16x8 ah1 = *(bf16x8*)&Khs[32 + lm][c * 16 + lq2 * 8];
                bf16x8 al1 = *(bf16x8*)&Kls[32 + lm][c * 16 + lq2 * 8];
                s[0] = __builtin_amdgcn_mfma_f32_32x32x16_bf16(ah0, qh[c],  s[0], 0, 0, 0);
                s[0] = __builtin_amdgcn_mfma_f32_32x32x16_bf16(ah0, qlr[c], s[0], 0, 0, 0);
                s[0] = __builtin_amdgcn_mfma_f32_32x32x16_bf16(al0, qh[c],  s[0], 0, 0, 0);
                s[1] = __builtin_amdgcn_mfma_f32_32x32x16_bf16(ah1, qh[c],  s[1], 0, 0, 0);
                s[1] = __builtin_amdgcn_mfma_f32_32x32x16_bf16(ah1, qlr[c], s[1], 0, 0, 0);
                s[1] = __builtin_amdgcn_mfma_f32_32x32x16_bf16(al1, qh[c],  s[1], 0, 0, 0);
            }

            if (kt * 64 + 63 > wave_qmin) {
                const int kbase = kt * 64 + 4 * lq2;
#pragma unroll
                for (int mt = 0; mt < 2; mt++)
#pragma unroll
                  for (int r = 0; r < 16; r++) {
                    int koff = (r & 3) + 8 * (r >> 2) + 32 * mt;
                    float L = s[mt][r] * L2SCALE;
                    if (kbase + koff > qg) L = NEGBIG;
                    s[mt][r] = L;
                  }
            } else {
#pragma unroll
                for (int mt = 0; mt < 2; mt++)
#pragma unroll
                  for (int r = 0; r < 16; r++) s[mt][r] *= L2SCALE;
            }

            float vmax = NEGBIG;
#pragma unroll
            for (int r = 0; r < 16; r++)
                vmax = fmaxf(vmax, fmaxf(s[0][r], s[1][r]));
            vmax = fmaxf(vmax, __shfl_xor(vmax, 32, 64));
            float mnew = fmaxf(m_run, vmax);
            float alpha = exp2f(m_run - mnew);
            float sum = 0.f;
#pragma unroll
            for (int mt = 0; mt < 2; mt++)
#pragma unroll
              for (int r = 0; r < 16; r++) {
                s[mt][r] = exp2f(s[mt][r] - mnew);
                sum += s[mt][r];
              }
            sum += __shfl_xor(sum, 32, 64);
            l_run = l_run * alpha + sum;
            m_run = mnew;
#pragma unroll
            for (int r = 0; r < 16; r++) { O0[r] *= alpha; O1[r] *= alpha; }

            bf16x8 pfrag[4];
#pragma unroll
            for (int mt = 0; mt < 2; mt++)
#pragma unroll
              for (int hh = 0; hh < 2; hh++) {
                BQ A, B;
#pragma unroll
                for (int i = 0; i < 4; i++) {
                    A.v[i] = (bf16)s[mt][8 * hh + i];
                    B.v[i] = (bf16)s[mt][8 * hh + 4 + i];
                }
                unsigned s0_ = lq2 ? A.u[0] : B.u[0];
                unsigned s1_ = lq2 ? A.u[1] : B.u[1];
                unsigned r0 = __shfl_xor(s0_, 32, 64);
                unsigned r1 = __shfl_xor(s1_, 32, 64);
                BF8 f;
                f.u[0] = lq2 ? r0 : A.u[0];
                f.u[1] = lq2 ? r1 : A.u[1];
                f.u[2] = lq2 ? B.u[0] : r0;
                f.u[3] = lq2 ? B.u[1] : r1;
                pfrag[mt * 2 + hh] = f.v;
              }

#pragma unroll
            for (int c = 0; c < 4; c++) {
                bf16x8 va0 = *(bf16x8*)&Vt[lm][c * 16 + lq2 * 8];
                bf16x8 va1 = *(bf16x8*)&Vt[32 + lm][c * 16 + lq2 * 8];
                O0 = __builtin_amdgcn_mfma_f32_32x32x16_bf16(va0, pfrag[c], O0, 0, 0, 0);
                O1 = __builtin_amdgcn_mfma_f32_32x32x16_bf16(va1, pfrag[c], O1, 0, 0, 0);
            }
        }

        if (more) {
#pragma unroll
            for (int i = 0; i < 4; i++) kc[i] = kn[i];
            vc[0] = vn[0]; vc[1] = vn[1];
        }
    }

    if (pid < 0) {
        const float inv = 1.0f / l_run;
        bf16* orow = attnbuf + ((size_t)b * SEQ + qg) * HID + h * HDIM;
#pragma unroll
        for (int g = 0; g < 4; g++) {
            int d0 = 8 * g + 4 * lq2;
            bf16x4 o0, o1;
#pragma unroll
            for (int i = 0; i < 4; i++) {
                o0[i] = (bf16)(O0[4 * g + i] * inv);
                o1[i] = (bf16)(O1[4 * g + i] * inv);
            }
            *(bf16x4*)(orow + d0)      = o0;
            *(bf16x4*)(orow + 32 + d0) = o1;
        }
    } else {
        bf16* prow = PartO + (((size_t)pid * 32 + bh) * 128 + ql_loc) * HDIM;
#pragma unroll
        for (int g = 0; g < 4; g++) {
            int d0 = 8 * g + 4 * lq2;
            bf16x4 o0, o1;
#pragma unroll
            for (int i = 0; i < 4; i++) {
                o0[i] = (bf16)O0[4 * g + i];
                o1[i] = (bf16)O1[4 * g + i];
            }
            *(bf16x4*)(prow + d0)      = o0;
            *(bf16x4*)(prow + 32 + d0) = o1;
        }
        if (lq2 == 0) {
            float2 ml = make_float2(m_run, l_run);
            *(float2*)&Mls[(((size_t)pid * 32 + bh) * 128 + ql_loc) * 2] = ml;
        }
    }
}

// ---------------------------------------------------------------------------
// Combine pass (unchanged).
// ---------------------------------------------------------------------------
__global__ __launch_bounds__(256) void attn_combine(
    const bf16* __restrict__ PartO, const float* __restrict__ Mls,
    bf16* __restrict__ attnbuf)
{
    const int tid = threadIdx.x;
    const int qt = 6 + blockIdx.x / 32;
    const int bh = blockIdx.x & 31;
    const int b = bh >> 4, h = bh & 15;
    const int qrow = tid >> 1;
    const int dh = (tid & 1) * 32;

    int pid0, nch;
    if (qt < 12) { pid0 = 2 * (qt - 6); nch = 2; }
    else         { pid0 = 12 + 3 * (qt - 12); nch = 3; }

    float mv[3], lv[3];
    float M = NEGBIG;
#pragma unroll
    for (int c = 0; c < 3; c++) {
        if (c < nch) {
            float2 ml = *(const float2*)&Mls[(((size_t)(pid0 + c) * 32 + bh) * 128 + qrow) * 2];
            mv[c] = ml.x; lv[c] = ml.y;
            M = fmaxf(M, mv[c]);
        }
    }
    float L = 0.f;
    float acc[32];
#pragma unroll
    for (int i = 0; i < 32; i++) acc[i] = 0.f;
#pragma unroll
    for (int c = 0; c < 3; c++) {
        if (c < nch) {
            float w = exp2f(mv[c] - M);
            L += w * lv[c];
            const bf16* p = PartO + (((size_t)(pid0 + c) * 32 + bh) * 128 + qrow) * HDIM + dh;
#pragma unroll
            for (int g = 0; g < 4; g++) {
                bf16x8 v = *(const bf16x8*)(p + g * 8);
#pragma unroll
                for (int i = 0; i < 8; i++) acc[g * 8 + i] += w * (float)v[i];
            }
        }
    }
    const float inv = 1.0f / L;
    bf16* orow = attnbuf + ((size_t)b * SEQ + qt * 128 + qrow) * HID + h * HDIM + dh;
#pragma unroll
    for (int g = 0; g < 4; g++) {
        bf16x8 o;
#pragma unroll
        for (int i = 0; i < 8; i++) o[i] = (bf16)(acc[g * 8 + i] * inv);
        *(bf16x8*)(orow + g * 8) = o;
    }
}

// ---------------------------------------------------------------------------
// GEMM2 (MFMA, plain bf16, r6-measured): out = attn @ W_out + b_out.
// 128m x 64n tile -> 512 blocks, 15.4 KB LDS, register-prefetch pipeline.
// ---------------------------------------------------------------------------
__global__ __launch_bounds__(256) void gemm_out_mfma(
    const bf16* __restrict__ Attn, const bf16* __restrict__ Wt,
    const float* __restrict__ bias, float* __restrict__ out)
{
    __shared__ __align__(16) bf16 Ah[64][40];    // Wt rows [n][k]
    __shared__ __align__(16) bf16 Bh[128][40];   // attn rows [m][k]

    const int tid = threadIdx.x;
    const int wave = tid >> 6, lane = tid & 63;
    const int lm = lane & 31, lq2 = lane >> 5;
    const int nBase = blockIdx.x * 64;
    const int mBase = blockIdx.y * 128;

    const int sr = tid >> 1, skc = (tid & 1) * 16;
    const int ar = tid >> 2, akc = (tid & 3) * 8;

    f32x16 acc[2];
#pragma unroll
    for (int nt = 0; nt < 2; nt++)
#pragma unroll
      for (int r = 0; r < 16; r++) acc[nt][r] = 0.f;

    bf16x8 cb[2], ca;
    {
        cb[0] = *(const bf16x8*)(Attn + (size_t)(mBase + sr) * HID + skc);
        cb[1] = *(const bf16x8*)(Attn + (size_t)(mBase + sr) * HID + skc + 8);
        ca    = *(const bf16x8*)(Wt + (size_t)(nBase + ar) * HID + akc);
    }

    for (int k0 = 0; k0 < HID; k0 += 32) {
        __syncthreads();
        *(bf16x8*)&Bh[sr][skc]     = cb[0];
        *(bf16x8*)&Bh[sr][skc + 8] = cb[1];
        *(bf16x8*)&Ah[ar][akc]     = ca;
        __syncthreads();

        bf16x8 nb[2] = {}, na = {};
        if (k0 + 32 < HID) {
            nb[0] = *(const bf16x8*)(Attn + (size_t)(mBase + sr) * HID + k0 + 32 + skc);
            nb[1] = *(const bf16x8*)(Attn + (size_t)(mBase + sr) * HID + k0 + 32 + skc + 8);
            na    = *(const bf16x8*)(Wt + (size_t)(nBase + ar) * HID + k0 + 32 + akc);
        }
#pragma unroll
        for (int kh = 0; kh < 2; kh++) {
            const int ko = kh * 16 + lq2 * 8;
            bf16x8 bA  = *(bf16x8*)&Bh[wave * 32 + lm][ko];
            bf16x8 aW0 = *(bf16x8*)&Ah[lm][ko];
            bf16x8 aW1 = *(bf16x8*)&Ah[32 + lm][ko];
            acc[0] = __builtin_amdgcn_mfma_f32_32x32x16_bf16(aW0, bA, acc[0], 0, 0, 0);
            acc[1] = __builtin_amdgcn_mfma_f32_32x32x16_bf16(aW1, bA, acc[1], 0, 0, 0);
        }
        cb[0] = nb[0]; cb[1] = nb[1]; ca = na;
    }

    const int m = mBase + wave * 32 + lm;
#pragma unroll
    for (int nt = 0; nt < 2; nt++) {
#pragma unroll
        for (int q4 = 0; q4 < 4; q4++) {
            int n = nBase + nt * 32 + 8 * q4 + 4 * lq2;
            float4 bv = *(const float4*)(bias + n);
            float4 o;
            o.x = acc[nt][q4 * 4 + 0] + bv.x;
            o.y = acc[nt][q4 * 4 + 1] + bv.y;
            o.z = acc[nt][q4 * 4 + 2] + bv.z;
            o.w = acc[nt][q4 * 4 + 3] + bv.w;
            *(float4*)(out + (size_t)m * HID + n) = o;
        }
    }
}

extern "C" void kernel_launch(void* const* d_in, const int* in_sizes, int n_in,
                              void* d_out, int out_size, void* d_ws, size_t ws_size,
                              hipStream_t stream) {
    const float* x    = (const float*)d_in[0];
    const float* Wqkv = (const float*)d_in[1];
    const float* bqkv = (const float*)d_in[2];
    const float* Wout = (const float*)d_in[3];
    const float* bout = (const float*)d_in[4];
    float* out = (float*)d_out;

    // workspace (bf16 elements), ~73.4 MB. Aliases (disjoint lifetimes):
    //   Xhi == attnbuf, Xlo == vtr, PartO == Wthi+Wtlo, Mls == vv
    const size_t NW  = (size_t)HID * 3 * HID;
    const size_t NWo = (size_t)HID * HID;
    const size_t NT  = (size_t)BATCH * NHEAD * SEQ * HDIM;
    bf16* Wthi = (bf16*)d_ws;
    bf16* Wtlo = Wthi + NW;
    bf16* Wot  = Wtlo + NW;
    bf16* qhi  = Wot + NWo;
    bf16* qlo  = qhi + NT;
    bf16* khi  = qlo + NT;
    bf16* klo  = khi + NT;
    bf16* vv   = klo + NT;
    bf16* attnbuf = vv + NT;
    bf16* Xhi  = attnbuf;
    bf16* Xlo  = attnbuf + NT;
    bf16* vtr  = Xlo;
    bf16* PartO = Wthi;
    float* Mls  = (float*)vv;

    // 0) fused preps
    prep_kernel<<<dim3(4096 + 768 + 256), 256, 0, stream>>>(
        x, Xhi, Xlo, Wqkv, Wthi, Wtlo, Wout, Wot);
    // 1) QKV projection (r10 tile + conflict-free quad staging, pitch 56)
    gemm_qkv_mfma<<<dim3(3 * HID / 128, BATCH * SEQ / 128), 256, 0, stream>>>(
        Xhi, Xlo, Wthi, Wtlo, bqkv, qhi, qlo, khi, klo, vv);
    // 2) V transpose for attention
    vtrans_kernel<<<dim3(SEQ / 64, BATCH * NHEAD), 256, 0, stream>>>(vv, vtr);
    // 3) split-K attention (960 items) + combine
    attn_kernel<<<dim3(960), 256, 0, stream>>>(
        qhi, qlo, khi, klo, vtr, attnbuf, PartO, Mls);
    attn_combine<<<dim3(320), 256, 0, stream>>>(PartO, Mls, attnbuf);
    // 4) output projection (r6 128x64 tiles, 512 blocks)
    gemm_out_mfma<<<dim3(HID / 64, BATCH * SEQ / 128), 256, 0, stream>>>(
        attnbuf, Wot, bout, out);
}

// Round 13
// 250.495 us; speedup vs baseline: 1.0814x; 1.0814x over previous
//
#include <hip/hip_runtime.h>
#include <hip/hip_bf16.h>

#define BATCH 2
#define SEQ 2048
#define HID 1024
#define NHEAD 16
#define HDIM 64
// softmax in exp2 domain: logit2 = (q.k) * TEMP_K/sqrt(d) * log2(e)
#define L2SCALE 180.3368800721f
#define NEGBIG (-1.0e30f)

typedef __bf16 bf16;
typedef __bf16 bf16x4 __attribute__((ext_vector_type(4)));
typedef __bf16 bf16x8 __attribute__((ext_vector_type(8)));
typedef float f32x16 __attribute__((ext_vector_type(16)));

union BQ  { bf16x4 v; unsigned u[2]; };
union BF8 { bf16x8 v; unsigned u[4]; };

// Split-K attention item table (heavy-first).
__device__ __constant__ int TAB_QT[30]  = {5,6,7,8,9,10,11,11,12,12,13,13,14,14,15,15, 4,10, 3,9,15, 2,8,14, 1,7,13, 0,6,12};
__device__ __constant__ int TAB_K0[30]  = {0,0,0,0,0,0,0,12,0,12,0,12,0,12,0,12, 0,12, 0,12,24, 0,12,24, 0,12,24, 0,12,24};
__device__ __constant__ int TAB_NIT[30] = {12,12,12,12,12,12,12,12,12,12,12,12,12,12,12,12, 10,10, 8,8,8, 6,6,6, 4,4,4, 2,2,2};
__device__ __constant__ int TAB_PID[30] = {-1,0,2,4,6,8,10,11,12,13,15,16,18,19,21,22, -1,9, -1,7,23, -1,5,20, -1,3,17, -1,1,14};

// ---------------------------------------------------------------------------
// Fused prep: xsplit (blocks 0..4095), W_qkv transpose+split (next 768),
// W_out transpose (last 256).
// ---------------------------------------------------------------------------
__device__ __forceinline__ void transpose_split_body(
    float (*T)[65], const float* __restrict__ W, bf16* __restrict__ Thi,
    bf16* __restrict__ Tlo, int K, int N, int kBase, int nBase, int tid)
{
    {
        const int k0 = tid >> 4;
        const int nc = (tid & 15) * 4;
#pragma unroll
        for (int kk = 0; kk < 4; kk++) {
            int k = k0 + kk * 16;
            float4 v = *(const float4*)(W + (size_t)(kBase + k) * N + nBase + nc);
            T[k][nc] = v.x; T[k][nc + 1] = v.y; T[k][nc + 2] = v.z; T[k][nc + 3] = v.w;
        }
    }
    __syncthreads();
    {
        const int n = tid >> 2;
        const int kc = (tid & 3) * 16;
        bf16x8 h0, h1, l0, l1;
#pragma unroll
        for (int j = 0; j < 8; j++) {
            float a = T[kc + j][n];
            float c = T[kc + 8 + j][n];
            bf16 ha = (bf16)a, hc = (bf16)c;
            h0[j] = ha; h1[j] = hc;
            l0[j] = (bf16)(a - (float)ha);
            l1[j] = (bf16)(c - (float)hc);
        }
        size_t dst = (size_t)(nBase + n) * K + kBase + kc;
        *(bf16x8*)(Thi + dst)     = h0;
        *(bf16x8*)(Thi + dst + 8) = h1;
        if (Tlo) {
            *(bf16x8*)(Tlo + dst)     = l0;
            *(bf16x8*)(Tlo + dst + 8) = l1;
        }
    }
}

__global__ __launch_bounds__(256) void prep_kernel(
    const float* __restrict__ X, bf16* __restrict__ Xhi, bf16* __restrict__ Xlo,
    const float* __restrict__ Wqkv, bf16* __restrict__ Wthi, bf16* __restrict__ Wtlo,
    const float* __restrict__ Wout, bf16* __restrict__ Wot)
{
    __shared__ float T[64][65];
    const int tid = threadIdx.x;
    const int bid = blockIdx.x;
    if (bid < 4096) {
        const int i = bid * 256 + tid;   // one float4 of X per thread
        float4 v = ((const float4*)X)[i];
        float xs[4] = {v.x, v.y, v.z, v.w};
        bf16x4 h, l;
#pragma unroll
        for (int j = 0; j < 4; j++) {
            h[j] = (bf16)xs[j];
            l[j] = (bf16)(xs[j] - (float)h[j]);
        }
        ((bf16x4*)Xhi)[i] = h;
        ((bf16x4*)Xlo)[i] = l;
    } else if (bid < 4096 + 768) {
        const int r = bid - 4096;                       // 16 kTiles x 48 nTiles
        transpose_split_body(T, Wqkv, Wthi, Wtlo, HID, 3 * HID,
                             (r / 48) * 64, (r % 48) * 64, tid);
    } else {
        const int r = bid - 4864;                       // 16 x 16
        transpose_split_body(T, Wout, Wot, nullptr, HID, HID,
                             (r / 16) * 64, (r % 16) * 64, tid);
    }
}

// ---------------------------------------------------------------------------
// Prep C: per-head V transpose [b][h][s][d] -> [b][h][d][s].
// ---------------------------------------------------------------------------
__global__ __launch_bounds__(256) void vtrans_kernel(
    const bf16* __restrict__ vv, bf16* __restrict__ vtr)
{
    __shared__ bf16 T[64][72];
    const int tid = threadIdx.x;
    const int bh = blockIdx.y;
    const int st = blockIdx.x;
    const int r  = tid >> 2;
    const int c0 = (tid & 3) * 16;
    const bf16* src = vv + ((size_t)bh * SEQ + st * 64) * HDIM;
    bf16x8 a = *(const bf16x8*)(src + (size_t)r * HDIM + c0);
    bf16x8 b = *(const bf16x8*)(src + (size_t)r * HDIM + c0 + 8);
    *(bf16x8*)&T[r][c0]     = a;
    *(bf16x8*)&T[r][c0 + 8] = b;
    __syncthreads();
    bf16x8 o0, o1;
#pragma unroll
    for (int i = 0; i < 8; i++) {
        o0[i] = T[c0 + i][r];
        o1[i] = T[c0 + 8 + i][r];
    }
    bf16* dst = vtr + ((size_t)bh * HDIM + r) * SEQ + st * 64 + c0;
    *(bf16x8*)(dst)     = o0;
    *(bf16x8*)(dst + 8) = o1;
}

// ---------------------------------------------------------------------------
// GEMM1 (MFMA, r10 exact — measured 82.4 us, MfmaUtil 31%): qkv = x @ W_qkv
// + b_qkv, pre-split bf16. LDS-staged X+W (pitch 40, pair staging), register
// double-buffer prefetch. r7/r9/r11/r12 falsified: streamed fragments,
// bigger tiles, and alternate staging layouts all regress; SQ_LDS_BANK_
// CONFLICT is invariant to layout here (structural b128 overhead).
// ---------------------------------------------------------------------------
__global__ __launch_bounds__(256) void gemm_qkv_mfma(
    const bf16* __restrict__ Xhi, const bf16* __restrict__ Xlo,
    const bf16* __restrict__ Wthi, const bf16* __restrict__ Wtlo,
    const float* __restrict__ bias,
    bf16* __restrict__ qhi, bf16* __restrict__ qlo,
    bf16* __restrict__ khi, bf16* __restrict__ klo, bf16* __restrict__ vv)
{
    __shared__ __align__(16) bf16 Xh[128][40];
    __shared__ __align__(16) bf16 Xl[128][40];
    __shared__ __align__(16) bf16 Wh[128][40];
    __shared__ __align__(16) bf16 Wl[128][40];

    const int tid = threadIdx.x;
    const int wave = tid >> 6, lane = tid & 63;
    const int lm = lane & 31, lq2 = lane >> 5;
    const int wave_s = wave & 1, wave_n = wave >> 1;
    const int nBase = blockIdx.x * 128;
    const int sBase = blockIdx.y * 128;
    const bool isV = (nBase >= 2 * HID);

    const int sr = tid >> 1, skc = (tid & 1) * 16;

    f32x16 acc[2][2];
#pragma unroll
    for (int st = 0; st < 2; st++)
#pragma unroll
      for (int nt = 0; nt < 2; nt++)
#pragma unroll
        for (int r = 0; r < 16; r++) acc[st][nt][r] = 0.f;

    bf16x8 cx[2], cw[2], cxl[2] = {}, cwl[2] = {};
    {
        size_t xsrc = (size_t)(sBase + sr) * HID + skc;
        size_t wsrc = (size_t)(nBase + sr) * HID + skc;
        cx[0] = *(const bf16x8*)(Xhi + xsrc);
        cx[1] = *(const bf16x8*)(Xhi + xsrc + 8);
        cw[0] = *(const bf16x8*)(Wthi + wsrc);
        cw[1] = *(const bf16x8*)(Wthi + wsrc + 8);
        if (!isV) {
            cxl[0] = *(const bf16x8*)(Xlo + xsrc);
            cxl[1] = *(const bf16x8*)(Xlo + xsrc + 8);
            cwl[0] = *(const bf16x8*)(Wtlo + wsrc);
            cwl[1] = *(const bf16x8*)(Wtlo + wsrc + 8);
        }
    }

    for (int k0 = 0; k0 < HID; k0 += 32) {
        __syncthreads();
        *(bf16x8*)&Xh[sr][skc]     = cx[0];
        *(bf16x8*)&Xh[sr][skc + 8] = cx[1];
        *(bf16x8*)&Wh[sr][skc]     = cw[0];
        *(bf16x8*)&Wh[sr][skc + 8] = cw[1];
        if (!isV) {
            *(bf16x8*)&Xl[sr][skc]     = cxl[0];
            *(bf16x8*)&Xl[sr][skc + 8] = cxl[1];
            *(bf16x8*)&Wl[sr][skc]     = cwl[0];
            *(bf16x8*)&Wl[sr][skc + 8] = cwl[1];
        }
        __syncthreads();

        // prefetch next k-tile (hidden under MFMA below)
        bf16x8 nx[2] = {}, nw[2] = {}, nxl[2] = {}, nwl[2] = {};
        if (k0 + 32 < HID) {
            size_t xsrc = (size_t)(sBase + sr) * HID + k0 + 32 + skc;
            size_t wsrc = (size_t)(nBase + sr) * HID + k0 + 32 + skc;
            nx[0] = *(const bf16x8*)(Xhi + xsrc);
            nx[1] = *(const bf16x8*)(Xhi + xsrc + 8);
            nw[0] = *(const bf16x8*)(Wthi + wsrc);
            nw[1] = *(const bf16x8*)(Wthi + wsrc + 8);
            if (!isV) {
                nxl[0] = *(const bf16x8*)(Xlo + xsrc);
                nxl[1] = *(const bf16x8*)(Xlo + xsrc + 8);
                nwl[0] = *(const bf16x8*)(Wtlo + wsrc);
                nwl[1] = *(const bf16x8*)(Wtlo + wsrc + 8);
            }
        }

#pragma unroll
        for (int kh = 0; kh < 2; kh++) {
            const int ko = kh * 16 + lq2 * 8;
            bf16x8 aWh[2], aWl[2], bXh[2], bXl[2];
#pragma unroll
            for (int nt = 0; nt < 2; nt++) {
                aWh[nt] = *(bf16x8*)&Wh[wave_n * 64 + nt * 32 + lm][ko];
                if (!isV) aWl[nt] = *(bf16x8*)&Wl[wave_n * 64 + nt * 32 + lm][ko];
            }
#pragma unroll
            for (int st = 0; st < 2; st++) {
                bXh[st] = *(bf16x8*)&Xh[wave_s * 64 + st * 32 + lm][ko];
                if (!isV) bXl[st] = *(bf16x8*)&Xl[wave_s * 64 + st * 32 + lm][ko];
            }
#pragma unroll
            for (int nt = 0; nt < 2; nt++)
#pragma unroll
              for (int st = 0; st < 2; st++) {
                acc[st][nt] = __builtin_amdgcn_mfma_f32_32x32x16_bf16(aWh[nt], bXh[st], acc[st][nt], 0, 0, 0);
                if (!isV) {
                    acc[st][nt] = __builtin_amdgcn_mfma_f32_32x32x16_bf16(aWh[nt], bXl[st], acc[st][nt], 0, 0, 0);
                    acc[st][nt] = __builtin_amdgcn_mfma_f32_32x32x16_bf16(aWl[nt], bXh[st], acc[st][nt], 0, 0, 0);
                }
              }
        }
        cx[0] = nx[0]; cx[1] = nx[1]; cw[0] = nw[0]; cw[1] = nw[1];
        cxl[0] = nxl[0]; cxl[1] = nxl[1]; cwl[0] = nwl[0]; cwl[1] = nwl[1];
    }

#pragma unroll
    for (int st = 0; st < 2; st++) {
        int s = sBase + wave_s * 64 + st * 32 + lm;
        int bb = s >> 11, ss = s & 2047;
#pragma unroll
        for (int nt = 0; nt < 2; nt++) {
#pragma unroll
            for (int q4 = 0; q4 < 4; q4++) {
                int n = nBase + wave_n * 64 + nt * 32 + 8 * q4 + 4 * lq2;
                float4 bv = *(const float4*)(bias + n);
                float vals[4];
                vals[0] = acc[st][nt][q4 * 4 + 0] + bv.x;
                vals[1] = acc[st][nt][q4 * 4 + 1] + bv.y;
                vals[2] = acc[st][nt][q4 * 4 + 2] + bv.z;
                vals[3] = acc[st][nt][q4 * 4 + 3] + bv.w;
                int which = n >> 10, h = (n >> 6) & 15, d = n & 63;
                size_t dst = (((size_t)bb * NHEAD + h) * SEQ + ss) * HDIM + d;
                if (which < 2) {
                    bf16x4 hi4, lo4;
#pragma unroll
                    for (int i = 0; i < 4; i++) {
                        hi4[i] = (bf16)vals[i];
                        lo4[i] = (bf16)(vals[i] - (float)hi4[i]);
                    }
                    bf16* ph = (which == 0) ? qhi : khi;
                    bf16* pl = (which == 0) ? qlo : klo;
                    *(bf16x4*)(ph + dst) = hi4;
                    *(bf16x4*)(pl + dst) = lo4;
                } else {
                    bf16x4 v4;
#pragma unroll
                    for (int i = 0; i < 4; i++) v4[i] = (bf16)vals[i];
                    *(bf16x4*)(vv + dst) = v4;
                }
            }
        }
    }
}

// ---------------------------------------------------------------------------
// MFMA flash attention, SPLIT-K (unchanged from round 6).
// ---------------------------------------------------------------------------
__global__ __launch_bounds__(256) void attn_kernel(
    const bf16* __restrict__ Qhi, const bf16* __restrict__ Qlo,
    const bf16* __restrict__ Khg, const bf16* __restrict__ Klg,
    const bf16* __restrict__ Vtr, bf16* __restrict__ attnbuf,
    bf16* __restrict__ PartO, float* __restrict__ Mls)
{
    __shared__ __align__(16) bf16 Khs[64][72];
    __shared__ __align__(16) bf16 Kls[64][72];
    __shared__ __align__(16) bf16 Vt [64][72];

    const int tid  = threadIdx.x;
    const int wave = tid >> 6;
    const int lane = tid & 63;
    const int lm   = lane & 31;
    const int lq2  = lane >> 5;

    const int kr  = tid >> 2;
    const int kd0 = (tid & 3) * 16;

    const int slot = blockIdx.x >> 5;
    const int bh   = blockIdx.x & 31;
    const int qt   = TAB_QT[slot];
    const int kt0  = TAB_K0[slot];
    const int nit  = TAB_NIT[slot];
    const int pid  = TAB_PID[slot];
    const int b = bh >> 4, h = bh & 15;
    const size_t headoff = ((size_t)b * NHEAD + h) * SEQ * HDIM;

    const int ql_loc = wave * 32 + lm;
    const int qg = qt * 128 + ql_loc;
    bf16x8 qh[4], qlr[4];
    {
        const bf16* qph = Qhi + headoff + (size_t)qg * HDIM;
        const bf16* qpl = Qlo + headoff + (size_t)qg * HDIM;
#pragma unroll
        for (int c = 0; c < 4; c++) {
            qh[c]  = *(const bf16x8*)(qph + c * 16 + lq2 * 8);
            qlr[c] = *(const bf16x8*)(qpl + c * 16 + lq2 * 8);
        }
    }

    f32x16 O0, O1;
#pragma unroll
    for (int r = 0; r < 16; r++) { O0[r] = 0.f; O1[r] = 0.f; }
    float m_run = NEGBIG, l_run = 0.f;

    const int wave_qmin = qt * 128 + wave * 32;
    const int ktend = kt0 + nit;

    bf16x8 kc[4], vc[2];
    {
        size_t kg = headoff + (size_t)(kt0 * 64 + kr) * HDIM + kd0;
        kc[0] = *(const bf16x8*)(Khg + kg);
        kc[1] = *(const bf16x8*)(Khg + kg + 8);
        kc[2] = *(const bf16x8*)(Klg + kg);
        kc[3] = *(const bf16x8*)(Klg + kg + 8);
        size_t vg = headoff + (size_t)kr * SEQ + kt0 * 64 + kd0;
        vc[0] = *(const bf16x8*)(Vtr + vg);
        vc[1] = *(const bf16x8*)(Vtr + vg + 8);
    }

    for (int kt = kt0; kt < ktend; kt++) {
        __syncthreads();
        *(bf16x8*)&Khs[kr][kd0]     = kc[0];
        *(bf16x8*)&Khs[kr][kd0 + 8] = kc[1];
        *(bf16x8*)&Kls[kr][kd0]     = kc[2];
        *(bf16x8*)&Kls[kr][kd0 + 8] = kc[3];
        *(bf16x8*)&Vt[kr][kd0]      = vc[0];
        *(bf16x8*)&Vt[kr][kd0 + 8]  = vc[1];
        __syncthreads();

        bf16x8 kn[4], vn[2];
        const bool more = (kt + 1 < ktend);
        if (more) {
            size_t kg = headoff + (size_t)((kt + 1) * 64 + kr) * HDIM + kd0;
            kn[0] = *(const bf16x8*)(Khg + kg);
            kn[1] = *(const bf16x8*)(Khg + kg + 8);
            kn[2] = *(const bf16x8*)(Klg + kg);
            kn[3] = *(const bf16x8*)(Klg + kg + 8);
            size_t vg = headoff + (size_t)kr * SEQ + (kt + 1) * 64 + kd0;
            vn[0] = *(const bf16x8*)(Vtr + vg);
            vn[1] = *(const bf16x8*)(Vtr + vg + 8);
        }

        if (kt * 64 <= wave_qmin + 31) {
            f32x16 s[2];
#pragma unroll
            for (int r = 0; r < 16; r++) { s[0][r] = 0.f; s[1][r] = 0.f; }
#pragma unroll
            for (int c = 0; c < 4; c++) {
                bf16x8 ah0 = *(bf16x8*)&Khs[lm][c * 16 + lq2 * 8];
                bf16x8 al0 = *(bf16x8*)&Kls[lm][c * 16 + lq2 * 8];
                bf16x8 ah1 = *(bf16x8*)&Khs[32 + lm][c * 16 + lq2 * 8];
                bf16x8 al1 = *(bf16x8*)&Kls[32 + lm][c * 16 + lq2 * 8];
                s[0] = __builtin_amdgcn_mfma_f32_32x32x16_bf16(ah0, qh[c],  s[0], 0, 0, 0);
                s[0] = __builtin_amdgcn_mfma_f32_32x32x16_bf16(ah0, qlr[c], s[0], 0, 0, 0);
                s[0] = __builtin_amdgcn_mfma_f32_32x32x16_bf16(al0, qh[c],  s[0], 0, 0, 0);
                s[1] = __builtin_amdgcn_mfma_f32_32x32x16_bf16(ah1, qh[c],  s[1], 0, 0, 0);
                s[1] = __builtin_amdgcn_mfma_f32_32x32x16_bf16(ah1, qlr[c], s[1], 0, 0, 0);
                s[1] = __builtin_amdgcn_mfma_f32_32x32x16_bf16(al1, qh[c],  s[1], 0, 0, 0);
            }

            if (kt * 64 + 63 > wave_qmin) {
                const int kbase = kt * 64 + 4 * lq2;
#pragma unroll
                for (int mt = 0; mt < 2; mt++)
#pragma unroll
                  for (int r = 0; r < 16; r++) {
                    int koff = (r & 3) + 8 * (r >> 2) + 32 * mt;
                    float L = s[mt][r] * L2SCALE;
                    if (kbase + koff > qg) L = NEGBIG;
                    s[mt][r] = L;
                  }
            } else {
#pragma unroll
                for (int mt = 0; mt < 2; mt++)
#pragma unroll
                  for (int r = 0; r < 16; r++) s[mt][r] *= L2SCALE;
            }

            float vmax = NEGBIG;
#pragma unroll
            for (int r = 0; r < 16; r++)
                vmax = fmaxf(vmax, fmaxf(s[0][r], s[1][r]));
            vmax = fmaxf(vmax, __shfl_xor(vmax, 32, 64));
            float mnew = fmaxf(m_run, vmax);
            float alpha = exp2f(m_run - mnew);
            float sum = 0.f;
#pragma unroll
            for (int mt = 0; mt < 2; mt++)
#pragma unroll
              for (int r = 0; r < 16; r++) {
                s[mt][r] = exp2f(s[mt][r] - mnew);
                sum += s[mt][r];
              }
            sum += __shfl_xor(sum, 32, 64);
            l_run = l_run * alpha + sum;
            m_run = mnew;
#pragma unroll
            for (int r = 0; r < 16; r++) { O0[r] *= alpha; O1[r] *= alpha; }

            bf16x8 pfrag[4];
#pragma unroll
            for (int mt = 0; mt < 2; mt++)
#pragma unroll
              for (int hh = 0; hh < 2; hh++) {
                BQ A, B;
#pragma unroll
                for (int i = 0; i < 4; i++) {
                    A.v[i] = (bf16)s[mt][8 * hh + i];
                    B.v[i] = (bf16)s[mt][8 * hh + 4 + i];
                }
                unsigned s0_ = lq2 ? A.u[0] : B.u[0];
                unsigned s1_ = lq2 ? A.u[1] : B.u[1];
                unsigned r0 = __shfl_xor(s0_, 32, 64);
                unsigned r1 = __shfl_xor(s1_, 32, 64);
                BF8 f;
                f.u[0] = lq2 ? r0 : A.u[0];
                f.u[1] = lq2 ? r1 : A.u[1];
                f.u[2] = lq2 ? B.u[0] : r0;
                f.u[3] = lq2 ? B.u[1] : r1;
                pfrag[mt * 2 + hh] = f.v;
              }

#pragma unroll
            for (int c = 0; c < 4; c++) {
                bf16x8 va0 = *(bf16x8*)&Vt[lm][c * 16 + lq2 * 8];
                bf16x8 va1 = *(bf16x8*)&Vt[32 + lm][c * 16 + lq2 * 8];
                O0 = __builtin_amdgcn_mfma_f32_32x32x16_bf16(va0, pfrag[c], O0, 0, 0, 0);
                O1 = __builtin_amdgcn_mfma_f32_32x32x16_bf16(va1, pfrag[c], O1, 0, 0, 0);
            }
        }

        if (more) {
#pragma unroll
            for (int i = 0; i < 4; i++) kc[i] = kn[i];
            vc[0] = vn[0]; vc[1] = vn[1];
        }
    }

    if (pid < 0) {
        const float inv = 1.0f / l_run;
        bf16* orow = attnbuf + ((size_t)b * SEQ + qg) * HID + h * HDIM;
#pragma unroll
        for (int g = 0; g < 4; g++) {
            int d0 = 8 * g + 4 * lq2;
            bf16x4 o0, o1;
#pragma unroll
            for (int i = 0; i < 4; i++) {
                o0[i] = (bf16)(O0[4 * g + i] * inv);
                o1[i] = (bf16)(O1[4 * g + i] * inv);
            }
            *(bf16x4*)(orow + d0)      = o0;
            *(bf16x4*)(orow + 32 + d0) = o1;
        }
    } else {
        bf16* prow = PartO + (((size_t)pid * 32 + bh) * 128 + ql_loc) * HDIM;
#pragma unroll
        for (int g = 0; g < 4; g++) {
            int d0 = 8 * g + 4 * lq2;
            bf16x4 o0, o1;
#pragma unroll
            for (int i = 0; i < 4; i++) {
                o0[i] = (bf16)O0[4 * g + i];
                o1[i] = (bf16)O1[4 * g + i];
            }
            *(bf16x4*)(prow + d0)      = o0;
            *(bf16x4*)(prow + 32 + d0) = o1;
        }
        if (lq2 == 0) {
            float2 ml = make_float2(m_run, l_run);
            *(float2*)&Mls[(((size_t)pid * 32 + bh) * 128 + ql_loc) * 2] = ml;
        }
    }
}

// ---------------------------------------------------------------------------
// Combine pass (unchanged).
// ---------------------------------------------------------------------------
__global__ __launch_bounds__(256) void attn_combine(
    const bf16* __restrict__ PartO, const float* __restrict__ Mls,
    bf16* __restrict__ attnbuf)
{
    const int tid = threadIdx.x;
    const int qt = 6 + blockIdx.x / 32;
    const int bh = blockIdx.x & 31;
    const int b = bh >> 4, h = bh & 15;
    const int qrow = tid >> 1;
    const int dh = (tid & 1) * 32;

    int pid0, nch;
    if (qt < 12) { pid0 = 2 * (qt - 6); nch = 2; }
    else         { pid0 = 12 + 3 * (qt - 12); nch = 3; }

    float mv[3], lv[3];
    float M = NEGBIG;
#pragma unroll
    for (int c = 0; c < 3; c++) {
        if (c < nch) {
            float2 ml = *(const float2*)&Mls[(((size_t)(pid0 + c) * 32 + bh) * 128 + qrow) * 2];
            mv[c] = ml.x; lv[c] = ml.y;
            M = fmaxf(M, mv[c]);
        }
    }
    float L = 0.f;
    float acc[32];
#pragma unroll
    for (int i = 0; i < 32; i++) acc[i] = 0.f;
#pragma unroll
    for (int c = 0; c < 3; c++) {
        if (c < nch) {
            float w = exp2f(mv[c] - M);
            L += w * lv[c];
            const bf16* p = PartO + (((size_t)(pid0 + c) * 32 + bh) * 128 + qrow) * HDIM + dh;
#pragma unroll
            for (int g = 0; g < 4; g++) {
                bf16x8 v = *(const bf16x8*)(p + g * 8);
#pragma unroll
                for (int i = 0; i < 8; i++) acc[g * 8 + i] += w * (float)v[i];
            }
        }
    }
    const float inv = 1.0f / L;
    bf16* orow = attnbuf + ((size_t)b * SEQ + qt * 128 + qrow) * HID + h * HDIM + dh;
#pragma unroll
    for (int g = 0; g < 4; g++) {
        bf16x8 o;
#pragma unroll
        for (int i = 0; i < 8; i++) o[i] = (bf16)(acc[g * 8 + i] * inv);
        *(bf16x8*)(orow + g * 8) = o;
    }
}

// ---------------------------------------------------------------------------
// GEMM2 (MFMA, plain bf16): out = attn @ W_out + b_out.
// r13 RETILE: 128m x 128n staged (the V-block mode of the measured-good r10
// gemm_qkv structure). DS:MFMA per thread-iter drops 9:4 (r6 128x64) ->
// 12:8. 256 uniform blocks, 20.5 KB LDS, pair staging pitch 40, register
// prefetch. Epilogue mapping = r9-verified 128x128 form.
// ---------------------------------------------------------------------------
__global__ __launch_bounds__(256) void gemm_out_mfma(
    const bf16* __restrict__ Attn, const bf16* __restrict__ Wt,
    const float* __restrict__ bias, float* __restrict__ out)
{
    __shared__ __align__(16) bf16 Ah[128][40];   // Wt rows [n][k]
    __shared__ __align__(16) bf16 Bh[128][40];   // attn rows [m][k]

    const int tid = threadIdx.x;
    const int wave = tid >> 6, lane = tid & 63;
    const int lm = lane & 31, lq2 = lane >> 5;
    const int wave_m = wave & 1, wave_n = wave >> 1;
    const int nBase = blockIdx.x * 128;
    const int mBase = blockIdx.y * 128;

    const int sr = tid >> 1, skc = (tid & 1) * 16;

    f32x16 acc[2][2];
#pragma unroll
    for (int st = 0; st < 2; st++)
#pragma unroll
      for (int nt = 0; nt < 2; nt++)
#pragma unroll
        for (int r = 0; r < 16; r++) acc[st][nt][r] = 0.f;

    bf16x8 ca[2], cb[2];
    {
        size_t asrc = (size_t)(nBase + sr) * HID + skc;
        size_t bsrc = (size_t)(mBase + sr) * HID + skc;
        ca[0] = *(const bf16x8*)(Wt + asrc);
        ca[1] = *(const bf16x8*)(Wt + asrc + 8);
        cb[0] = *(const bf16x8*)(Attn + bsrc);
        cb[1] = *(const bf16x8*)(Attn + bsrc + 8);
    }

    for (int k0 = 0; k0 < HID; k0 += 32) {
        __syncthreads();
        *(bf16x8*)&Ah[sr][skc]     = ca[0];
        *(bf16x8*)&Ah[sr][skc + 8] = ca[1];
        *(bf16x8*)&Bh[sr][skc]     = cb[0];
        *(bf16x8*)&Bh[sr][skc + 8] = cb[1];
        __syncthreads();

        bf16x8 na[2] = {}, nb[2] = {};
        if (k0 + 32 < HID) {
            size_t asrc = (size_t)(nBase + sr) * HID + k0 + 32 + skc;
            size_t bsrc = (size_t)(mBase + sr) * HID + k0 + 32 + skc;
            na[0] = *(const bf16x8*)(Wt + asrc);
            na[1] = *(const bf16x8*)(Wt + asrc + 8);
            nb[0] = *(const bf16x8*)(Attn + bsrc);
            nb[1] = *(const bf16x8*)(Attn + bsrc + 8);
        }

#pragma unroll
        for (int kh = 0; kh < 2; kh++) {
            const int ko = kh * 16 + lq2 * 8;
            bf16x8 aW[2], bB[2];
#pragma unroll
            for (int nt = 0; nt < 2; nt++)
                aW[nt] = *(bf16x8*)&Ah[wave_n * 64 + nt * 32 + lm][ko];
#pragma unroll
            for (int st = 0; st < 2; st++)
                bB[st] = *(bf16x8*)&Bh[wave_m * 64 + st * 32 + lm][ko];
#pragma unroll
            for (int nt = 0; nt < 2; nt++)
#pragma unroll
              for (int st = 0; st < 2; st++)
                acc[st][nt] = __builtin_amdgcn_mfma_f32_32x32x16_bf16(aW[nt], bB[st], acc[st][nt], 0, 0, 0);
        }
        ca[0] = na[0]; ca[1] = na[1];
        cb[0] = nb[0]; cb[1] = nb[1];
    }

#pragma unroll
    for (int st = 0; st < 2; st++) {
        int m = mBase + wave_m * 64 + st * 32 + lm;
#pragma unroll
        for (int nt = 0; nt < 2; nt++) {
#pragma unroll
            for (int q4 = 0; q4 < 4; q4++) {
                int n = nBase + wave_n * 64 + nt * 32 + 8 * q4 + 4 * lq2;
                float4 bv = *(const float4*)(bias + n);
                float4 o;
                o.x = acc[st][nt][q4 * 4 + 0] + bv.x;
                o.y = acc[st][nt][q4 * 4 + 1] + bv.y;
                o.z = acc[st][nt][q4 * 4 + 2] + bv.z;
                o.w = acc[st][nt][q4 * 4 + 3] + bv.w;
                *(float4*)(out + (size_t)m * HID + n) = o;
            }
        }
    }
}

extern "C" void kernel_launch(void* const* d_in, const int* in_sizes, int n_in,
                              void* d_out, int out_size, void* d_ws, size_t ws_size,
                              hipStream_t stream) {
    const float* x    = (const float*)d_in[0];
    const float* Wqkv = (const float*)d_in[1];
    const float* bqkv = (const float*)d_in[2];
    const float* Wout = (const float*)d_in[3];
    const float* bout = (const float*)d_in[4];
    float* out = (float*)d_out;

    // workspace (bf16 elements), ~73.4 MB. Aliases (disjoint lifetimes):
    //   Xhi == attnbuf, Xlo == vtr, PartO == Wthi+Wtlo, Mls == vv
    const size_t NW  = (size_t)HID * 3 * HID;
    const size_t NWo = (size_t)HID * HID;
    const size_t NT  = (size_t)BATCH * NHEAD * SEQ * HDIM;
    bf16* Wthi = (bf16*)d_ws;
    bf16* Wtlo = Wthi + NW;
    bf16* Wot  = Wtlo + NW;
    bf16* qhi  = Wot + NWo;
    bf16* qlo  = qhi + NT;
    bf16* khi  = qlo + NT;
    bf16* klo  = khi + NT;
    bf16* vv   = klo + NT;
    bf16* attnbuf = vv + NT;
    bf16* Xhi  = attnbuf;
    bf16* Xlo  = attnbuf + NT;
    bf16* vtr  = Xlo;
    bf16* PartO = Wthi;
    float* Mls  = (float*)vv;

    // 0) fused preps
    prep_kernel<<<dim3(4096 + 768 + 256), 256, 0, stream>>>(
        x, Xhi, Xlo, Wqkv, Wthi, Wtlo, Wout, Wot);
    // 1) QKV projection (r10 exact)
    gemm_qkv_mfma<<<dim3(3 * HID / 128, BATCH * SEQ / 128), 256, 0, stream>>>(
        Xhi, Xlo, Wthi, Wtlo, bqkv, qhi, qlo, khi, klo, vv);
    // 2) V transpose for attention
    vtrans_kernel<<<dim3(SEQ / 64, BATCH * NHEAD), 256, 0, stream>>>(vv, vtr);
    // 3) split-K attention (960 items) + combine
    attn_kernel<<<dim3(960), 256, 0, stream>>>(
        qhi, qlo, khi, klo, vtr, attnbuf, PartO, Mls);
    attn_combine<<<dim3(320), 256, 0, stream>>>(PartO, Mls, attnbuf);
    // 4) output projection (r13 128x128 staged, 256 uniform blocks)
    gemm_out_mfma<<<dim3(HID / 128, BATCH * SEQ / 128), 256, 0, stream>>>(
        attnbuf, Wot, bout, out);
}